// Round 19
// baseline (134.050 us; speedup 1.0000x reference)
//
#include <hip/hip_runtime.h>
#include <hip/hip_bf16.h>

typedef __attribute__((ext_vector_type(8))) short short8;
typedef __attribute__((ext_vector_type(4))) float f32x4;
typedef __attribute__((ext_vector_type(16))) float f32x16;
typedef __attribute__((ext_vector_type(2))) unsigned int u32x2;
typedef __attribute__((ext_vector_type(4))) unsigned int u32x4;

#define SLAB 9216      // bytes per slab: 144 rows x 64B (32 bf16)

// involution swizzle: XOR bank-group bits (4-5) with row bits (7-8)
__device__ __forceinline__ unsigned sw(unsigned off) {
  return off ^ (((off >> 7) & 3u) << 4);
}

__device__ __forceinline__ unsigned pk2(float lo, float hi) {
  union { __hip_bfloat162 h; unsigned u; } c;
  c.h = __float22bfloat162_rn(float2{lo, hi});
  return c.u;
}

// one-time: ker (fp32, N*K x F x C) -> bf16 32x32x16-A-fragment-linear in ws
// frag(ch,nk,kq,ft): lane l holds W[f=ft*32+(l&31), c=ch*32+kq*16+(l>>5)*8 .. +8]
extern "C" __global__ void w_prep(const float* __restrict__ ker, u32x4* __restrict__ wsw) {
  const int nk = blockIdx.x % 36;
  const int ch = blockIdx.x / 36;
  const int lane = threadIdx.x & 63;
  const int w = threadIdx.x >> 6;      // 0..3
  const int kq = w >> 1, ft = w & 1;
  const float* src = ker + (size_t)(nk * 64 + ft * 32 + (lane & 31)) * 64
                         + ch * 32 + kq * 16 + (lane >> 5) * 8;
  f32x4 a0 = *(const f32x4*)src;
  f32x4 a1 = *(const f32x4*)(src + 4);
  u32x4 h = { pk2(a0.x, a0.y), pk2(a0.z, a0.w), pk2(a1.x, a1.y), pk2(a1.z, a1.w) };
  wsw[((ch * 36 + nk) * 4 + kq * 2 + ft) * 64 + lane] = h;
}

// one k-iteration (32x32x16, r15-style 1-deep B pipeline): rotate-in W
// (window +3), prefetch B(k+1) into bnxt, setprio-wrapped 4-MFMA cluster
// on bcur, roll.
#define KSTEP(KK, WREG, S2, K2, PF) do {                                       \
    const int _wo = (((S2) & 1) * 36 + ((S2) >> 1) * 9 + (K2)) * 256 + ftl;    \
    short8 _n0 = wqb[_wo];                                                     \
    short8 _n1 = wqb[_wo + 128];                                               \
    if (PF) {                                                                  \
      const unsigned _kq = cb + (unsigned)(((((KK) + 1)) >> 2) * 512) + poff[((KK) + 1) & 3]; \
      bnxt0 = *(const short8*)(xs + _kq);                                      \
      bnxt1 = *(const short8*)(xs + (_kq ^ 32u));                              \
      bnxt2 = *(const short8*)(xs + (_kq + 2048u));                            \
      bnxt3 = *(const short8*)(xs + ((_kq + 2048u) ^ 32u));                    \
    }                                                                          \
    __builtin_amdgcn_s_setprio(1);                                             \
    acc0 = __builtin_amdgcn_mfma_f32_32x32x16_bf16(WREG[0], bcur0, acc0, 0, 0, 0); \
    acc1 = __builtin_amdgcn_mfma_f32_32x32x16_bf16(WREG[0], bcur2, acc1, 0, 0, 0); \
    acc0 = __builtin_amdgcn_mfma_f32_32x32x16_bf16(WREG[1], bcur1, acc0, 0, 0, 0); \
    acc1 = __builtin_amdgcn_mfma_f32_32x32x16_bf16(WREG[1], bcur3, acc1, 0, 0, 0); \
    __builtin_amdgcn_s_setprio(0);                                             \
    WREG[0] = _n0; WREG[1] = _n1;                                              \
    if (PF) { bcur0 = bnxt0; bcur1 = bnxt1; bcur2 = bnxt2; bcur3 = bnxt3; }    \
  } while (0)

extern "C" __global__ __launch_bounds__(256, 3)
void glc_mfma(const float* __restrict__ x, const short8* __restrict__ wsw,
              const int* __restrict__ nb, float* __restrict__ out) {
  __shared__ __align__(16) char xs[2 * SLAB];

  // XCD-locality swizzle (r14-proven): one XCD's resident blocks share one
  // (b,a) x-slice (~3.8 MB, L2-resident). 3000 = 8*375, bijective.
  const int d = blockIdx.x;
  const int l = (d & 7) * 375 + (d >> 3);
  const int u  = l % 25;
  const int tt = (l / 25) % 5;
  const int a  = (l / 125) % 3;
  const int b  = l / 375;
  const int t0 = tt * 64;

  const int tid  = threadIdx.x;
  const int lane = tid & 63;
  const int wave = tid >> 6;           // 0..3
  const int ft   = wave >> 1;          // which 32-f tile
  const int cp   = wave & 1;           // which pair of 32-col tiles
  const int ftl  = ft * 64;

  const int l31 = lane & 31, hi = lane >> 5;
  unsigned poff[4];
#pragma unroll
  for (int m = 0; m < 4; ++m)
    poff[m] = sw((unsigned)((2 * m + l31) * 64 + hi * 16));

  f32x16 acc0 = {0.f,0.f,0.f,0.f,0.f,0.f,0.f,0.f,0.f,0.f,0.f,0.f,0.f,0.f,0.f,0.f};
  f32x16 acc1 = acc0;

  // ---- per-thread staging load offsets (1152 f32x4 over 256 threads) ----
  int goff[5];
#pragma unroll
  for (int j = 0; j < 5; ++j) {
    const int idx = j * 256 + tid;      // 0..1151 used (j=4 active only for tid<128)
    const int r = idx >> 3;
    const int q = idx & 7;
    int t = t0 + (r >> 1); if (t > 299) t = 299;   // clamp; garbage discarded
    goff[j] = t * 9600 + (r & 1) * 64 + q * 4;     // x fp32 offset (v,ch terms per step)
  }
  const float* xb = x + (size_t)b * (300 * 9600) + (size_t)a * 3200;
  const short8* wqb = wsw + lane;
  const int* nbu = nb + u * 4;

  f32x4 sr[5];
  auto stage_load = [&](int snx) {
    const int add = nbu[snx >> 1] * 128 + (snx & 1) * 32;
#pragma unroll
    for (int j = 0; j < 5; ++j)
      if (j < 4 || tid < 128)
        sr[j] = *(const f32x4*)(xb + goff[j] + add);
  };
  auto stage_write = [&](int snx) {
    char* dst = xs + (snx & 1) * SLAB;
#pragma unroll
    for (int j = 0; j < 5; ++j)
      if (j < 4 || tid < 128) {
        const int idx = j * 256 + tid;
        const int r = idx >> 3, q = idx & 7;
        u32x2 h = { pk2(sr[j].x, sr[j].y), pk2(sr[j].z, sr[j].w) };
        *(u32x2*)(dst + sw((unsigned)(r * 64 + q * 8))) = h;
      }
  };

  // ---- prologue: W(step0, taps 0..2) into 3-deep window; stage step 0 ----
  short8 wA[2], wB[2], wC[2];
  {
    wA[0] = wqb[0 * 256 + ftl]; wA[1] = wqb[0 * 256 + ftl + 128];
    wB[0] = wqb[1 * 256 + ftl]; wB[1] = wqb[1 * 256 + ftl + 128];
    wC[0] = wqb[2 * 256 + ftl]; wC[1] = wqb[2 * 256 + ftl + 128];
  }
  stage_load(0);
  stage_write(0);
  __syncthreads();

  short8 bcur0, bcur1, bcur2, bcur3;
  short8 bnxt0, bnxt1, bnxt2, bnxt3;

  // ---- main loop: 8 steps of (n = s>>1, ch = s&1) ----
#pragma unroll 1
  for (int s = 0; s < 8; ++s) {
    const int sn = (s < 7) ? (s + 1) : 7;      // s=7: dummy in-bounds reloads
    const unsigned cb = (unsigned)((s & 1) * SLAB + cp * 4096);
    // B(k=0) prologue reads — start the ds chain right after the barrier
    {
      const unsigned kq0 = cb + poff[0];
      bcur0 = *(const short8*)(xs + kq0);
      bcur1 = *(const short8*)(xs + (kq0 ^ 32u));
      bcur2 = *(const short8*)(xs + (kq0 + 2048u));
      bcur3 = *(const short8*)(xs + ((kq0 + 2048u) ^ 32u));
    }
    if (s < 7) stage_load(s + 1);              // HBM loads overlap compute
    KSTEP(0, wA, s, 3, 1);  KSTEP(1, wB, s, 4, 1);  KSTEP(2, wC, s, 5, 1);
    KSTEP(3, wA, s, 6, 1);  KSTEP(4, wB, s, 7, 1);  KSTEP(5, wC, s, 8, 1);
    KSTEP(6, wA, sn, 0, 1); KSTEP(7, wB, sn, 1, 1); KSTEP(8, wC, sn, 2, 0);
    if (s < 7) {
      stage_write(s + 1);                      // vmcnt wait lands after compute
      __syncthreads();
    }
  }

  // ---- epilogue (32x32 C layout, r14-verified): col = (cp*2+i)*32 + l31;
  //      f = ft*32 + rg*8 + hi*4 + (reg&3) ----
  const f32x4 z4 = (f32x4){0.f, 0.f, 0.f, 0.f};
#pragma unroll
  for (int i = 0; i < 2; ++i) {
    const f32x16 A = i ? acc1 : acc0;
    const int col = (cp * 2 + i) * 32 + l31;   // 0..127 within u (t-rel, p-minor)
    const int t = t0 + (col >> 1);
    const int p = col & 1;
    if (t < 300) {
      float* dst = out + ((size_t)((b * 300 + t) * 3 + a) * 50 + (u * 2 + p)) * 64
                       + ft * 32 + hi * 4;
      const bool valid = (t < 292);     // t>=292: zero-pad tail
      f32x4 v0 = valid ? (f32x4){A[0],  A[1],  A[2],  A[3]}  : z4;
      f32x4 v1 = valid ? (f32x4){A[4],  A[5],  A[6],  A[7]}  : z4;
      f32x4 v2 = valid ? (f32x4){A[8],  A[9],  A[10], A[11]} : z4;
      f32x4 v3 = valid ? (f32x4){A[12], A[13], A[14], A[15]} : z4;
      __builtin_nontemporal_store(v0, (f32x4*)(dst + 0));
      __builtin_nontemporal_store(v1, (f32x4*)(dst + 8));
      __builtin_nontemporal_store(v2, (f32x4*)(dst + 16));
      __builtin_nontemporal_store(v3, (f32x4*)(dst + 24));
    }
  }
}

extern "C" void kernel_launch(void* const* d_in, const int* in_sizes, int n_in,
                              void* d_out, int out_size, void* d_ws, size_t ws_size,
                              hipStream_t stream) {
  const float* x   = (const float*)d_in[0];
  const float* ker = (const float*)d_in[1];
  const int*   nb  = (const int*)d_in[2];
  float* out = (float*)d_out;

  w_prep<<<dim3(72), dim3(256), 0, stream>>>(ker, (u32x4*)d_ws);
  // grid: 3000 independent 4-wave blocks (XCD-swizzled inside the kernel)
  glc_mfma<<<dim3(3000), dim3(256), 0, stream>>>(x, (const short8*)d_ws, nb, out);
}

// Round 20
// 113.212 us; speedup vs baseline: 1.1841x; 1.1841x over previous
//
#include <hip/hip_runtime.h>
#include <hip/hip_bf16.h>

typedef __attribute__((ext_vector_type(8))) short short8;
typedef __attribute__((ext_vector_type(4))) float f32x4;
typedef __attribute__((ext_vector_type(2))) unsigned int u32x2;
typedef __attribute__((ext_vector_type(4))) unsigned int u32x4;

#define SLAB 9216      // bytes per slab: 144 rows x 64B (32 bf16)

// involution swizzle: XOR bank-group bits (4-5) with row bits (7-8)
__device__ __forceinline__ unsigned sw(unsigned off) {
  return off ^ (((off >> 7) & 3u) << 4);
}

__device__ __forceinline__ unsigned pk2(float lo, float hi) {
  union { __hip_bfloat162 h; unsigned u; } c;
  c.h = __float22bfloat162_rn(float2{lo, hi});
  return c.u;
}

// one-time: ker (fp32, N*K x F x C) -> bf16 fragment-linear in ws
// frag(ch,nk,ft,lane) holds W[f=ft*16+(lane&15), c=ch*32+(lane>>4)*8 .. +8]
extern "C" __global__ void w_prep(const float* __restrict__ ker, u32x4* __restrict__ wsw) {
  const int nk = blockIdx.x % 36;
  const int ch = blockIdx.x / 36;
  const int lane = threadIdx.x & 63;
  const int ft = threadIdx.x >> 6;
  const float* src = ker + (size_t)(nk * 64 + ft * 16 + (lane & 15)) * 64
                         + ch * 32 + (lane >> 4) * 8;
  f32x4 a0 = *(const f32x4*)src;
  f32x4 a1 = *(const f32x4*)(src + 4);
  u32x4 h = { pk2(a0.x, a0.y), pk2(a0.z, a0.w), pk2(a1.x, a1.y), pk2(a1.z, a1.w) };
  wsw[((ch * 36 + nk) * 4 + ft) * 64 + lane] = h;
}

// one k-iteration: rotate-in W (window +3), prefetch B(k+1) into bnxt,
// setprio-wrapped 8-MFMA cluster on bcur, roll pipeline.
#define KSTEP(KK, WREG, S2, K2, PF) do {                                       \
    const int _wo = (((S2) & 1) * 9216) + (((S2) >> 1) * 2304) + ((K2) * 256) + fhl; \
    short8 _n0 = wqb[_wo];                                                     \
    short8 _n1 = wqb[_wo + 64];                                                \
    if (PF) {                                                                  \
      const unsigned _kq = cb + (unsigned)(((((KK) + 1)) >> 2) * 512) + poff[((KK) + 1) & 3]; \
      bnxt0 = *(const short8*)(xs + _kq);                                      \
      bnxt1 = *(const short8*)(xs + _kq + 1024u);                              \
      bnxt2 = *(const short8*)(xs + _kq + 2048u);                              \
      bnxt3 = *(const short8*)(xs + _kq + 3072u);                              \
    }                                                                          \
    __builtin_amdgcn_s_setprio(1);                                             \
    acc[0][0] = __builtin_amdgcn_mfma_f32_16x16x32_bf16(WREG[0], bcur0, acc[0][0], 0, 0, 0); \
    acc[1][0] = __builtin_amdgcn_mfma_f32_16x16x32_bf16(WREG[1], bcur0, acc[1][0], 0, 0, 0); \
    acc[0][1] = __builtin_amdgcn_mfma_f32_16x16x32_bf16(WREG[0], bcur1, acc[0][1], 0, 0, 0); \
    acc[1][1] = __builtin_amdgcn_mfma_f32_16x16x32_bf16(WREG[1], bcur1, acc[1][1], 0, 0, 0); \
    acc[0][2] = __builtin_amdgcn_mfma_f32_16x16x32_bf16(WREG[0], bcur2, acc[0][2], 0, 0, 0); \
    acc[1][2] = __builtin_amdgcn_mfma_f32_16x16x32_bf16(WREG[1], bcur2, acc[1][2], 0, 0, 0); \
    acc[0][3] = __builtin_amdgcn_mfma_f32_16x16x32_bf16(WREG[0], bcur3, acc[0][3], 0, 0, 0); \
    acc[1][3] = __builtin_amdgcn_mfma_f32_16x16x32_bf16(WREG[1], bcur3, acc[1][3], 0, 0, 0); \
    __builtin_amdgcn_s_setprio(0);                                             \
    WREG[0] = _n0; WREG[1] = _n1;                                              \
    if (PF) { bcur0 = bnxt0; bcur1 = bnxt1; bcur2 = bnxt2; bcur3 = bnxt3; }    \
  } while (0)

extern "C" __global__ __launch_bounds__(256, 3)
void glc_mfma(const float* __restrict__ x, const short8* __restrict__ wsw,
              const int* __restrict__ nb, float* __restrict__ out) {
  __shared__ __align__(16) char xs[2 * SLAB];

  // XCD-locality swizzle (r14-proven): one XCD's resident blocks share one
  // (b,a) x-slice (~3.8 MB, L2-resident). 3000 = 8*375, bijective.
  const int d = blockIdx.x;
  const int l = (d & 7) * 375 + (d >> 3);
  const int u  = l % 25;
  const int tt = (l / 25) % 5;
  const int a  = (l / 125) % 3;
  const int b  = l / 375;
  const int t0 = tt * 64;

  const int tid  = threadIdx.x;
  const int lane = tid & 63;
  const int wave = tid >> 6;           // 0..3
  const int fhalf = wave >> 1;         // which pair of f-tiles (f 0-31 / 32-63)
  const int tq   = wave & 1;           // which 4 col-tiles (of 8) of this u
  const int fhl  = fhalf * 128;

  const int rl = lane & 15, gq = lane >> 4;
  unsigned poff[4];
#pragma unroll
  for (int m = 0; m < 4; ++m)
    poff[m] = sw((unsigned)((2 * m + rl) * 64 + gq * 16));

  f32x4 acc[2][4];
#pragma unroll
  for (int j = 0; j < 2; ++j)
#pragma unroll
    for (int i = 0; i < 4; ++i) acc[j][i] = (f32x4){0.f, 0.f, 0.f, 0.f};

  // ---- per-thread staging load offsets (1152 f32x4 over 256 threads) ----
  int goff[5];
#pragma unroll
  for (int j = 0; j < 5; ++j) {
    const int idx = j * 256 + tid;      // 0..1151 used (j=4 active only for tid<128)
    const int r = idx >> 3;
    const int q = idx & 7;
    int t = t0 + (r >> 1); if (t > 299) t = 299;   // clamp; garbage discarded
    goff[j] = t * 9600 + (r & 1) * 64 + q * 4;     // x fp32 offset (v,ch terms per step)
  }
  const float* xb = x + (size_t)b * (300 * 9600) + (size_t)a * 3200;
  const short8* wqb = wsw + lane;
  const int* nbu = nb + u * 4;

  f32x4 sr[5];
  auto stage_load = [&](int snx) {
    const int add = nbu[snx >> 1] * 128 + (snx & 1) * 32;
#pragma unroll
    for (int j = 0; j < 5; ++j)
      if (j < 4 || tid < 128)
        sr[j] = *(const f32x4*)(xb + goff[j] + add);
  };
  auto stage_write = [&](int snx) {
    char* dst = xs + (snx & 1) * SLAB;
#pragma unroll
    for (int j = 0; j < 5; ++j)
      if (j < 4 || tid < 128) {
        const int idx = j * 256 + tid;
        const int r = idx >> 3, q = idx & 7;
        u32x2 h = { pk2(sr[j].x, sr[j].y), pk2(sr[j].z, sr[j].w) };
        *(u32x2*)(dst + sw((unsigned)(r * 64 + q * 8))) = h;
      }
  };

  // ---- prologue: W(0,0..2) into 3-deep window; stage step 0 ----
  short8 wA[2], wB[2], wC[2];
  {
    const int o0 = 0 * 256 + fhl, o1 = 1 * 256 + fhl, o2 = 2 * 256 + fhl;
    wA[0] = wqb[o0]; wA[1] = wqb[o0 + 64];
    wB[0] = wqb[o1]; wB[1] = wqb[o1 + 64];
    wC[0] = wqb[o2]; wC[1] = wqb[o2 + 64];
  }
  stage_load(0);
  stage_write(0);
  __syncthreads();

  short8 bcur0, bcur1, bcur2, bcur3;
  short8 bnxt0, bnxt1, bnxt2, bnxt3;

  // ---- main loop: 8 steps of (n = s>>1, ch = s&1) ----
#pragma unroll 1
  for (int s = 0; s < 8; ++s) {
    const int sn = (s < 7) ? (s + 1) : 7;      // s=7: dummy in-bounds reloads
    const unsigned cb = (unsigned)((s & 1) * SLAB + tq * 4096);
    // B(k=0) prologue reads — start the ds chain right after the barrier
    {
      const unsigned kq0 = cb + poff[0];
      bcur0 = *(const short8*)(xs + kq0);
      bcur1 = *(const short8*)(xs + kq0 + 1024u);
      bcur2 = *(const short8*)(xs + kq0 + 2048u);
      bcur3 = *(const short8*)(xs + kq0 + 3072u);
    }
    if (s < 7) stage_load(s + 1);              // HBM loads overlap compute
    KSTEP(0, wA, s, 3, 1);  KSTEP(1, wB, s, 4, 1);  KSTEP(2, wC, s, 5, 1);
    KSTEP(3, wA, s, 6, 1);  KSTEP(4, wB, s, 7, 1);  KSTEP(5, wC, s, 8, 1);
    KSTEP(6, wA, sn, 0, 1); KSTEP(7, wB, sn, 1, 1); KSTEP(8, wC, sn, 2, 0);
    if (s < 7) {
      stage_write(s + 1);                      // vmcnt wait lands after compute
      __syncthreads();
    }
  }

  // ---- epilogue: D tile (j,i): col = (tq*4+i)*16+rl, f = fhalf*32+j*16+gq*4 ----
  const int fb = fhalf * 32 + gq * 4;
  const f32x4 z4 = (f32x4){0.f, 0.f, 0.f, 0.f};
#pragma unroll
  for (int i = 0; i < 4; ++i) {
    const int col = (tq * 4 + i) * 16 + rl;   // 0..127 within u (t-rel, p-minor)
    const int t = t0 + (col >> 1);
    const int p = col & 1;
    if (t < 300) {
      float* dst = out + ((size_t)((b * 300 + t) * 3 + a) * 50 + (u * 2 + p)) * 64 + fb;
      const bool valid = (t < 292);     // t>=292: zero-pad tail
#pragma unroll
      for (int j = 0; j < 2; ++j) {
        f32x4 v = valid ? acc[j][i] : z4;
        __builtin_nontemporal_store(v, (f32x4*)(dst + j * 16));
      }
    }
  }
}

extern "C" void kernel_launch(void* const* d_in, const int* in_sizes, int n_in,
                              void* d_out, int out_size, void* d_ws, size_t ws_size,
                              hipStream_t stream) {
  const float* x   = (const float*)d_in[0];
  const float* ker = (const float*)d_in[1];
  const int*   nb  = (const int*)d_in[2];
  float* out = (float*)d_out;

  w_prep<<<dim3(72), dim3(256), 0, stream>>>(ker, (u32x4*)d_ws);
  // grid: 3000 independent 4-wave blocks (XCD-swizzled inside the kernel)
  glc_mfma<<<dim3(3000), dim3(256), 0, stream>>>(x, (const short8*)d_ws, nb, out);
}